// Round 5
// baseline (445.030 us; speedup 1.0000x reference)
//
#include <hip/hip_runtime.h>
#include <math.h>

#define BS_TOK 16384   // B*S
#define DIM    2048    // D
#define NEXP   64      // E
#define DHID   1024    // D/2
#define GKS    4       // gate k-split
#define KSL    (DIM / GKS)

typedef __attribute__((ext_vector_type(8))) _Float16 f16x8;
typedef __attribute__((ext_vector_type(4))) float    f32x4;

#define GLOBAL_AS const __attribute__((address_space(1))) void*
#define LDS_AS    __attribute__((address_space(3))) void*
#define GLDS16(g, l) __builtin_amdgcn_global_load_lds((GLOBAL_AS)(g), (LDS_AS)(l), 16, 0, 0)

__device__ __forceinline__ float gelu_f(float x) {
  return 0.5f * x * (1.0f + erff(x * 0.70710678118654752440f));
}

// ================= prep: gate (blocks 0..1023) | LN (1024..5119) | W1 cast (5120..6143) ==========
#define GATE_NB 1024
#define LN_NB   4096
#define CAST_NB 1024

__global__ __launch_bounds__(256) void prep_kernel(const float* __restrict__ X,
                                                   const float* __restrict__ Wg,
                                                   const float* __restrict__ gamma,
                                                   const float* __restrict__ beta,
                                                   const float* __restrict__ W1,
                                                   _Float16* __restrict__ H,
                                                   _Float16* __restrict__ W1h,
                                                   float* __restrict__ logitsP) {
  const int bid = blockIdx.x;
  const int tid = threadIdx.x;
  __shared__ float sX[16][68];   // gate staging [k][m], padded
  __shared__ float sW[16][68];   // gate staging [k][e], padded

  if (bid < GATE_NB) {
    // ---- gate partials: logitsP[ks] = X[:, ks-slice] . Wg[:, ks-slice]^T ----
    // 64x64 tile, 4x4 micro (16 acc VGPRs), k-split 4, plain float4 stores.
    const int m0   = (bid >> 2) * 64;
    const int k0   = (bid & 3) * KSL;
    const int srow = tid >> 2;      // 0..63 staging row
    const int skq  = tid & 3;       // k-quad
    const int ty   = tid >> 4;      // 0..15 token group (4 tokens)
    const int tx   = tid & 15;      // 0..15 expert group (4 experts)
    const float* xb = X  + (size_t)(m0 + srow) * DIM + k0 + skq * 4;
    const float* wb = Wg + (size_t)srow * DIM + k0 + skq * 4;
    float acc[4][4] = {};
    float4 rx = *(const float4*)xb;
    float4 rw = *(const float4*)wb;
    for (int kt = 0; kt < KSL; kt += 16) {
      __syncthreads();
      sX[skq * 4 + 0][srow] = rx.x;
      sX[skq * 4 + 1][srow] = rx.y;
      sX[skq * 4 + 2][srow] = rx.z;
      sX[skq * 4 + 3][srow] = rx.w;
      sW[skq * 4 + 0][srow] = rw.x;
      sW[skq * 4 + 1][srow] = rw.y;
      sW[skq * 4 + 2][srow] = rw.z;
      sW[skq * 4 + 3][srow] = rw.w;
      const int ktn = (kt + 16 < KSL) ? kt + 16 : 0;   // harmless reload on last iter
      rx = *(const float4*)(xb + ktn);
      rw = *(const float4*)(wb + ktn);
      __syncthreads();
#pragma unroll
      for (int k = 0; k < 16; ++k) {
        const float4 a4 = *(const float4*)&sX[k][ty * 4];
        const float4 b4 = *(const float4*)&sW[k][tx * 4];
        const float av[4] = {a4.x, a4.y, a4.z, a4.w};
        const float bv[4] = {b4.x, b4.y, b4.z, b4.w};
#pragma unroll
        for (int i = 0; i < 4; ++i)
#pragma unroll
          for (int j = 0; j < 4; ++j) acc[i][j] += av[i] * bv[j];
      }
    }
    float* op = logitsP + (size_t)(bid & 3) * (BS_TOK * NEXP)
              + (size_t)(m0 + ty * 4) * NEXP + tx * 4;
#pragma unroll
    for (int i = 0; i < 4; ++i) {
      float4 o;
      o.x = acc[i][0]; o.y = acc[i][1]; o.z = acc[i][2]; o.w = acc[i][3];
      *(float4*)(op + (size_t)i * NEXP) = o;
    }
  } else if (bid < GATE_NB + LN_NB) {
    // ---- LayerNorm -> f16 H : one wave per token, no LDS, no barriers ----
    const int w    = tid >> 6, lane = tid & 63;
    const int t    = (bid - GATE_NB) * 4 + w;
    const float* xr = X + (size_t)t * DIM;
    float4 xv[8];
#pragma unroll
    for (int j = 0; j < 4; ++j) {
      const int c0 = (j * 64 + lane) * 8;
      xv[j * 2]     = *(const float4*)(xr + c0);
      xv[j * 2 + 1] = *(const float4*)(xr + c0 + 4);
    }
    float s = 0.f, q = 0.f;
#pragma unroll
    for (int j = 0; j < 8; ++j) {
      s += (xv[j].x + xv[j].y) + (xv[j].z + xv[j].w);
      q += (xv[j].x * xv[j].x + xv[j].y * xv[j].y) + (xv[j].z * xv[j].z + xv[j].w * xv[j].w);
    }
#pragma unroll
    for (int off = 32; off > 0; off >>= 1) {
      s += __shfl_xor(s, off);
      q += __shfl_xor(q, off);
    }
    const float mu  = s * (1.0f / DIM);
    const float var = q * (1.0f / DIM) - mu * mu;
    const float rs  = rsqrtf(var + 1e-5f);
#pragma unroll
    for (int j = 0; j < 4; ++j) {
      const int c0 = (j * 64 + lane) * 8;
      const float4 g0 = *(const float4*)(gamma + c0);
      const float4 g1 = *(const float4*)(gamma + c0 + 4);
      const float4 b0 = *(const float4*)(beta + c0);
      const float4 b1 = *(const float4*)(beta + c0 + 4);
      const float4 a = xv[j * 2], b = xv[j * 2 + 1];
      f16x8 h;
      h[0] = (_Float16)((a.x - mu) * rs * g0.x + b0.x);
      h[1] = (_Float16)((a.y - mu) * rs * g0.y + b0.y);
      h[2] = (_Float16)((a.z - mu) * rs * g0.z + b0.z);
      h[3] = (_Float16)((a.w - mu) * rs * g0.w + b0.w);
      h[4] = (_Float16)((b.x - mu) * rs * g1.x + b1.x);
      h[5] = (_Float16)((b.y - mu) * rs * g1.y + b1.y);
      h[6] = (_Float16)((b.z - mu) * rs * g1.z + b1.z);
      h[7] = (_Float16)((b.w - mu) * rs * g1.w + b1.w);
      *(f16x8*)(H + (size_t)t * DIM + c0) = h;
    }
  } else {
    // ---- W1 fp32 -> f16 ----
    const int i = ((bid - GATE_NB - LN_NB) * 256 + tid) * 8;
    const float4 a = *(const float4*)(W1 + i);
    const float4 b = *(const float4*)(W1 + i + 4);
    f16x8 o;
    o[0] = (_Float16)a.x; o[1] = (_Float16)a.y; o[2] = (_Float16)a.z; o[3] = (_Float16)a.w;
    o[4] = (_Float16)b.x; o[5] = (_Float16)b.y; o[6] = (_Float16)b.z; o[7] = (_Float16)b.w;
    *(f16x8*)(W1h + i) = o;
  }
}

// ------- predictor GEMM: H1 = gelu(H . W1^T); z[t] += sum_n H1*W2 (fused) -------
// XCD-swizzled 1-D grid; MFMA-order LDS layout (conflict-free b128 frag reads);
// double-buffered one-barrier K-loop: barrier drains only loads issued a full
// iteration ago, prefetch for k+1 issued after the barrier is never drained early.
__global__ __launch_bounds__(256) void g2_kernel(const _Float16* __restrict__ H,
                                                 const _Float16* __restrict__ W1h,
                                                 const float* __restrict__ W2,
                                                 float* __restrict__ diffz) {
  // layout per buffer: group g(=row>>4) in [0,8): halves offset g*512 + lane*8
  // (lane = quad*16 + r encodes [quad=k-octet][r=row&15]) -> frag read == staging dest
  __shared__ __align__(16) _Float16 sA[2][4096];
  __shared__ __align__(16) _Float16 sB[2][4096];
  const int bid = blockIdx.x;
  const int c   = bid & 7;
  const int j   = bid >> 3;
  const int m0  = (c * 16 + (j >> 3)) * 128;
  const int n0  = (j & 7) * 128;
  const int tid  = threadIdx.x;
  const int w    = tid >> 6, lane = tid & 63;
  const int wr   = w >> 1,  wc   = w & 1;
  const int col  = lane & 15, quad = lane >> 4;
  const int r    = lane & 15, q = lane >> 4;     // staging row-in-group / k-octet
  const int gA   = w * 2;                         // this wave stages groups gA, gA+1
  const _Float16* srcA0 = H   + (size_t)(m0 + gA * 16 + r) * DIM + q * 8;
  const _Float16* srcA1 = srcA0 + (size_t)16 * DIM;
  const _Float16* srcB0 = W1h + (size_t)(n0 + gA * 16 + r) * DIM + q * 8;
  const _Float16* srcB1 = srcB0 + (size_t)16 * DIM;
  const int dOff = gA * 512 + lane * 8;
  f32x4 acc[4][4] = {};
  // prologue: stage tile 0 into buffer 0
  GLDS16(srcA0, &sA[0][dOff]);
  GLDS16(srcA1, &sA[0][dOff + 512]);
  GLDS16(srcB0, &sB[0][dOff]);
  GLDS16(srcB1, &sB[0][dOff + 512]);
  for (int it = 0; it < 64; ++it) {
    const int cb = it & 1;
    __syncthreads();                      // drains cur-tile loads (issued last iter)
    if (it < 63) {                        // prefetch next tile into other buffer
      const int kt2 = (it + 1) << 5;
      const int nb  = cb ^ 1;
      GLDS16(srcA0 + kt2, &sA[nb][dOff]);
      GLDS16(srcA1 + kt2, &sA[nb][dOff + 512]);
      GLDS16(srcB0 + kt2, &sB[nb][dOff]);
      GLDS16(srcB1 + kt2, &sB[nb][dOff + 512]);
    }
    f16x8 af[4], bf[4];
#pragma unroll
    for (int mi = 0; mi < 4; ++mi)
      af[mi] = *(const f16x8*)&sA[cb][(wr * 4 + mi) * 512 + lane * 8];
#pragma unroll
    for (int ni = 0; ni < 4; ++ni)
      bf[ni] = *(const f16x8*)&sB[cb][(wc * 4 + ni) * 512 + lane * 8];
#pragma unroll
    for (int mi = 0; mi < 4; ++mi)
#pragma unroll
      for (int ni = 0; ni < 4; ++ni)
        acc[mi][ni] = __builtin_amdgcn_mfma_f32_16x16x32_f16(af[mi], bf[ni], acc[mi][ni], 0, 0, 0);
  }
  // epilogue: gelu -> * W2 -> reduce over the 128 n-cols this block owns
  float w2v[4];
#pragma unroll
  for (int ni = 0; ni < 4; ++ni) w2v[ni] = W2[n0 + wc * 64 + ni * 16 + col];
#pragma unroll
  for (int mi = 0; mi < 4; ++mi) {
#pragma unroll
    for (int reg = 0; reg < 4; ++reg) {
      float v = 0.f;
#pragma unroll
      for (int ni = 0; ni < 4; ++ni) v += gelu_f(acc[mi][ni][reg]) * w2v[ni];
      v += __shfl_xor(v, 1);
      v += __shfl_xor(v, 2);
      v += __shfl_xor(v, 4);
      v += __shfl_xor(v, 8);
      if (col == 0)
        atomicAdd(diffz + m0 + wr * 64 + mi * 16 + quad * 4 + reg, v);
    }
  }
}

// ---------------- per-token finalize: one wave per token, 32 tokens/block ----------------
__global__ __launch_bounds__(256) void finalize_kernel(const float* __restrict__ logitsP,
                                                       const float* __restrict__ diffz,
                                                       float* __restrict__ out_idx,
                                                       float* __restrict__ out_scores,
                                                       float* __restrict__ out_probs,
                                                       float* __restrict__ out_imp,
                                                       float* __restrict__ out_load) {
  const int tid  = threadIdx.x;
  const int w    = tid >> 6, lane = tid & 63;
  const size_t PS = (size_t)BS_TOK * NEXP;
  float acc_imp = 0.f, acc_load = 0.f;
  for (int it = 0; it < 8; ++it) {
    const int t    = blockIdx.x * 32 + it * 4 + w;
    const float* lp = logitsP + (size_t)t * NEXP + lane;
    const float L  = ((lp[0] + lp[PS]) + lp[2 * PS]) + lp[3 * PS];
    const float z  = diffz[t];
    const float d  = 1.0f / (1.0f + expf(-z));
    const float l  = L / (1.0f + d);          // TEMP == 1
    // fused top-2 tournament butterfly; key = (value desc, index asc).
    // After 6 steps every lane holds global (v1,i1,v2,i2); v1 doubles as softmax max.
    float v1 = l; int i1 = lane;
    float v2 = -INFINITY; int i2 = 0;
#pragma unroll
    for (int off = 32; off > 0; off >>= 1) {
      const float ov1 = __shfl_xor(v1, off); const int oi1 = __shfl_xor(i1, off);
      const float ov2 = __shfl_xor(v2, off); const int oi2 = __shfl_xor(i2, off);
      const bool bwin = (ov1 > v1) || (ov1 == v1 && oi1 < i1);
      const float w1 = bwin ? ov1 : v1; const int wi1 = bwin ? oi1 : i1;
      const float l1 = bwin ? v1 : ov1; const int li1 = bwin ? i1 : oi1;
      const float c2 = bwin ? ov2 : v2; const int ci2 = bwin ? oi2 : i2;
      const bool s2w = (c2 > l1) || (c2 == l1 && ci2 < li1);
      v2 = s2w ? c2 : l1; i2 = s2w ? ci2 : li1;
      v1 = w1; i1 = wi1;
    }
    // softmax using v1 as max
    float p = expf(l - v1);
    float s = p;
#pragma unroll
    for (int off = 32; off > 0; off >>= 1) s += __shfl_xor(s, off);
    p /= s;
    const float p1 = __shfl(p, i1);
    const float p2 = __shfl(p, i2);
    const float s1 = (1.0f - p1) + p1;        // straight-through, fp32-faithful
    const float s2 = (1.0f - p2) + p2;
    const float den = fmaxf(s1 + s2, 1e-9f);
    if (lane == 0) {
      out_idx[t * 2]        = (float)i1;
      out_idx[t * 2 + 1]    = (float)i2;
      out_scores[t * 2]     = s1 / den;
      out_scores[t * 2 + 1] = s2 / den;
    }
    out_probs[(size_t)t * NEXP + lane] = p;
    acc_imp  += p;
    acc_load += (lane == i1 || lane == i2) ? 1.0f : 0.0f;
  }
  __shared__ float s_imp[256];
  __shared__ float s_hard[256];
  s_imp[tid]  = acc_imp;
  s_hard[tid] = acc_load;
  __syncthreads();
  if (tid < 64) {
    const float inv = 1.0f / (float)BS_TOK;
    const float si = s_imp[tid] + s_imp[64 + tid] + s_imp[128 + tid] + s_imp[192 + tid];
    const float sl = s_hard[tid] + s_hard[64 + tid] + s_hard[128 + tid] + s_hard[192 + tid];
    atomicAdd(out_imp + tid, si * inv);
    atomicAdd(out_load + tid, sl * inv);
  }
}

extern "C" void kernel_launch(void* const* d_in, const int* in_sizes, int n_in,
                              void* d_out, int out_size, void* d_ws, size_t ws_size,
                              hipStream_t stream) {
  (void)in_sizes; (void)n_in; (void)out_size; (void)ws_size;
  const float* X     = (const float*)d_in[0];
  const float* Wg    = (const float*)d_in[1];
  const float* gamma = (const float*)d_in[2];
  const float* beta  = (const float*)d_in[3];
  const float* W1    = (const float*)d_in[4];
  const float* W2    = (const float*)d_in[5];
  float* out = (float*)d_out;

  char* ws = (char*)d_ws;
  _Float16* H       = (_Float16*)(ws);                    // 64 MB
  _Float16* W1h     = (_Float16*)(ws + 67108864ull);      // 4 MB
  float*    logitsP = (float*)  (ws + 71303168ull);       // 16 MB (4 k-split partials)
  float*    diffz   = (float*)  (ws + 88080384ull);       // 64 KB

  // out layout (all float32): idx[32768] | scores[32768] | probs[1048576] | imp[64] | load[64]
  float* out_idx    = out;
  float* out_scores = out + 32768;
  float* out_probs  = out + 65536;
  float* out_imp    = out + 1114112;
  float* out_load   = out + 1114176;

  hipMemsetAsync(diffz, 0, 65536ull, stream);
  hipMemsetAsync(out_imp, 0, 512ull, stream);
  prep_kernel<<<GATE_NB + LN_NB + CAST_NB, 256, 0, stream>>>(X, Wg, gamma, beta, W1,
                                                             H, W1h, logitsP);
  g2_kernel<<<(DHID / 128) * (BS_TOK / 128), 256, 0, stream>>>(H, W1h, W2, diffz);
  finalize_kernel<<<BS_TOK / 32, 256, 0, stream>>>(logitsP, diffz, out_idx, out_scores,
                                                   out_probs, out_imp, out_load);
}

// Round 6
// 421.849 us; speedup vs baseline: 1.0550x; 1.0550x over previous
//
#include <hip/hip_runtime.h>
#include <math.h>

#define BS_TOK 16384   // B*S
#define DIM    2048    // D
#define NEXP   64      // E
#define DHID   1024    // D/2
#define GKS    4       // gate k-split
#define KSL    (DIM / GKS)

typedef __attribute__((ext_vector_type(8))) _Float16 f16x8;
typedef __attribute__((ext_vector_type(4))) float    f32x4;

#define GLOBAL_AS const __attribute__((address_space(1))) void*
#define LDS_AS    __attribute__((address_space(3))) void*
#define GLDS16(g, l) __builtin_amdgcn_global_load_lds((GLOBAL_AS)(g), (LDS_AS)(l), 16, 0, 0)

__device__ __forceinline__ float gelu_f(float x) {
  return 0.5f * x * (1.0f + erff(x * 0.70710678118654752440f));
}

// ================= prep: gate (blocks 0..1023) | LN (1024..5119) | W1 cast (5120..6143) ==========
#define GATE_NB 1024
#define LN_NB   4096
#define CAST_NB 1024

__global__ __launch_bounds__(256) void prep_kernel(const float* __restrict__ X,
                                                   const float* __restrict__ Wg,
                                                   const float* __restrict__ gamma,
                                                   const float* __restrict__ beta,
                                                   const float* __restrict__ W1,
                                                   _Float16* __restrict__ H,
                                                   _Float16* __restrict__ W1h,
                                                   float* __restrict__ logitsP) {
  const int bid = blockIdx.x;
  const int tid = threadIdx.x;
  __shared__ float sX[16][68];   // gate staging [k][m], padded
  __shared__ float sW[16][68];   // gate staging [k][e], padded

  if (bid < GATE_NB) {
    // ---- gate partials: logitsP[ks] = X[:, ks-slice] . Wg[:, ks-slice]^T ----
    // 64x64 tile, 4x4 micro (16 acc VGPRs), k-split 4, plain float4 stores.
    const int m0   = (bid >> 2) * 64;
    const int k0   = (bid & 3) * KSL;
    const int srow = tid >> 2;      // 0..63 staging row
    const int skq  = tid & 3;       // k-quad
    const int ty   = tid >> 4;      // 0..15 token group (4 tokens)
    const int tx   = tid & 15;      // 0..15 expert group (4 experts)
    const float* xb = X  + (size_t)(m0 + srow) * DIM + k0 + skq * 4;
    const float* wb = Wg + (size_t)srow * DIM + k0 + skq * 4;
    float acc[4][4] = {};
    float4 rx = *(const float4*)xb;
    float4 rw = *(const float4*)wb;
    for (int kt = 0; kt < KSL; kt += 16) {
      __syncthreads();
      sX[skq * 4 + 0][srow] = rx.x;
      sX[skq * 4 + 1][srow] = rx.y;
      sX[skq * 4 + 2][srow] = rx.z;
      sX[skq * 4 + 3][srow] = rx.w;
      sW[skq * 4 + 0][srow] = rw.x;
      sW[skq * 4 + 1][srow] = rw.y;
      sW[skq * 4 + 2][srow] = rw.z;
      sW[skq * 4 + 3][srow] = rw.w;
      const int ktn = (kt + 16 < KSL) ? kt + 16 : 0;   // harmless reload on last iter
      rx = *(const float4*)(xb + ktn);
      rw = *(const float4*)(wb + ktn);
      __syncthreads();
#pragma unroll
      for (int k = 0; k < 16; ++k) {
        const float4 a4 = *(const float4*)&sX[k][ty * 4];
        const float4 b4 = *(const float4*)&sW[k][tx * 4];
        const float av[4] = {a4.x, a4.y, a4.z, a4.w};
        const float bv[4] = {b4.x, b4.y, b4.z, b4.w};
#pragma unroll
        for (int i = 0; i < 4; ++i)
#pragma unroll
          for (int j = 0; j < 4; ++j) acc[i][j] += av[i] * bv[j];
      }
    }
    float* op = logitsP + (size_t)(bid & 3) * (BS_TOK * NEXP)
              + (size_t)(m0 + ty * 4) * NEXP + tx * 4;
#pragma unroll
    for (int i = 0; i < 4; ++i) {
      float4 o;
      o.x = acc[i][0]; o.y = acc[i][1]; o.z = acc[i][2]; o.w = acc[i][3];
      *(float4*)(op + (size_t)i * NEXP) = o;
    }
  } else if (bid < GATE_NB + LN_NB) {
    // ---- LayerNorm -> f16 H : one wave per token, no LDS, no barriers ----
    const int w    = tid >> 6, lane = tid & 63;
    const int t    = (bid - GATE_NB) * 4 + w;
    const float* xr = X + (size_t)t * DIM;
    float4 xv[8];
#pragma unroll
    for (int j = 0; j < 4; ++j) {
      const int c0 = (j * 64 + lane) * 8;
      xv[j * 2]     = *(const float4*)(xr + c0);
      xv[j * 2 + 1] = *(const float4*)(xr + c0 + 4);
    }
    float s = 0.f, q = 0.f;
#pragma unroll
    for (int j = 0; j < 8; ++j) {
      s += (xv[j].x + xv[j].y) + (xv[j].z + xv[j].w);
      q += (xv[j].x * xv[j].x + xv[j].y * xv[j].y) + (xv[j].z * xv[j].z + xv[j].w * xv[j].w);
    }
#pragma unroll
    for (int off = 32; off > 0; off >>= 1) {
      s += __shfl_xor(s, off);
      q += __shfl_xor(q, off);
    }
    const float mu  = s * (1.0f / DIM);
    const float var = q * (1.0f / DIM) - mu * mu;
    const float rs  = rsqrtf(var + 1e-5f);
#pragma unroll
    for (int j = 0; j < 4; ++j) {
      const int c0 = (j * 64 + lane) * 8;
      const float4 g0 = *(const float4*)(gamma + c0);
      const float4 g1 = *(const float4*)(gamma + c0 + 4);
      const float4 b0 = *(const float4*)(beta + c0);
      const float4 b1 = *(const float4*)(beta + c0 + 4);
      const float4 a = xv[j * 2], b = xv[j * 2 + 1];
      f16x8 h;
      h[0] = (_Float16)((a.x - mu) * rs * g0.x + b0.x);
      h[1] = (_Float16)((a.y - mu) * rs * g0.y + b0.y);
      h[2] = (_Float16)((a.z - mu) * rs * g0.z + b0.z);
      h[3] = (_Float16)((a.w - mu) * rs * g0.w + b0.w);
      h[4] = (_Float16)((b.x - mu) * rs * g1.x + b1.x);
      h[5] = (_Float16)((b.y - mu) * rs * g1.y + b1.y);
      h[6] = (_Float16)((b.z - mu) * rs * g1.z + b1.z);
      h[7] = (_Float16)((b.w - mu) * rs * g1.w + b1.w);
      *(f16x8*)(H + (size_t)t * DIM + c0) = h;
    }
  } else {
    // ---- W1 fp32 -> f16 ----
    const int i = ((bid - GATE_NB - LN_NB) * 256 + tid) * 8;
    const float4 a = *(const float4*)(W1 + i);
    const float4 b = *(const float4*)(W1 + i + 4);
    f16x8 o;
    o[0] = (_Float16)a.x; o[1] = (_Float16)a.y; o[2] = (_Float16)a.z; o[3] = (_Float16)a.w;
    o[4] = (_Float16)b.x; o[5] = (_Float16)b.y; o[6] = (_Float16)b.z; o[7] = (_Float16)b.w;
    *(f16x8*)(W1h + i) = o;
  }
}

// ------- predictor GEMM: H1 = gelu(H . W1^T); z[t] += sum_n H1*W2 (fused) -------
// XCD-swizzled grid; conflict-free MFMA-order LDS layout; double-buffered with
// COMPILE-TIME buffer indices (2x manual unroll) and consume-reads issued BEFORE
// the prefetch so no vmcnt wait lands between prefetch and ds_read. The barrier's
// structural vmcnt(0) drains only loads issued a full MFMA-phase earlier.
__global__ __launch_bounds__(256) void g2_kernel(const _Float16* __restrict__ H,
                                                 const _Float16* __restrict__ W1h,
                                                 const float* __restrict__ W2,
                                                 float* __restrict__ diffz) {
  __shared__ __align__(16) _Float16 sA0[4096];
  __shared__ __align__(16) _Float16 sA1[4096];
  __shared__ __align__(16) _Float16 sB0[4096];
  __shared__ __align__(16) _Float16 sB1[4096];
  const int bid = blockIdx.x;
  const int c   = bid & 7;
  const int j   = bid >> 3;
  const int m0  = (c * 16 + (j >> 3)) * 128;
  const int n0  = (j & 7) * 128;
  const int tid  = threadIdx.x;
  const int w    = tid >> 6, lane = tid & 63;
  const int wr   = w >> 1,  wc   = w & 1;
  const int col  = lane & 15, quad = lane >> 4;
  const int r    = lane & 15, q = lane >> 4;     // staging row-in-group / k-octet
  const int gA   = w * 2;                         // this wave stages groups gA, gA+1
  const _Float16* srcA0 = H   + (size_t)(m0 + gA * 16 + r) * DIM + q * 8;
  const _Float16* srcA1 = srcA0 + (size_t)16 * DIM;
  const _Float16* srcB0 = W1h + (size_t)(n0 + gA * 16 + r) * DIM + q * 8;
  const _Float16* srcB1 = srcB0 + (size_t)16 * DIM;
  const int dOff = gA * 512 + lane * 8;
  f32x4 acc[4][4] = {};
  // prologue: stage tile 0 into buffer 0
  GLDS16(srcA0, sA0 + dOff);
  GLDS16(srcA1, sA0 + dOff + 512);
  GLDS16(srcB0, sB0 + dOff);
  GLDS16(srcB1, sB0 + dOff + 512);
  for (int it2 = 0; it2 < 32; ++it2) {
    // ---- phase A: consume buf0 (tile 2*it2), prefetch tile 2*it2+1 -> buf1 ----
    {
      __syncthreads();
      f16x8 af[4], bf[4];
#pragma unroll
      for (int mi = 0; mi < 4; ++mi)
        af[mi] = *(const f16x8*)(sA0 + (wr * 4 + mi) * 512 + lane * 8);
#pragma unroll
      for (int ni = 0; ni < 4; ++ni)
        bf[ni] = *(const f16x8*)(sB0 + (wc * 4 + ni) * 512 + lane * 8);
      const int kt = (2 * it2 + 1) * 32;
      GLDS16(srcA0 + kt, sA1 + dOff);
      GLDS16(srcA1 + kt, sA1 + dOff + 512);
      GLDS16(srcB0 + kt, sB1 + dOff);
      GLDS16(srcB1 + kt, sB1 + dOff + 512);
#pragma unroll
      for (int mi = 0; mi < 4; ++mi)
#pragma unroll
        for (int ni = 0; ni < 4; ++ni)
          acc[mi][ni] = __builtin_amdgcn_mfma_f32_16x16x32_f16(af[mi], bf[ni], acc[mi][ni], 0, 0, 0);
    }
    // ---- phase B: consume buf1 (tile 2*it2+1), prefetch tile 2*it2+2 -> buf0 ----
    {
      __syncthreads();
      f16x8 af[4], bf[4];
#pragma unroll
      for (int mi = 0; mi < 4; ++mi)
        af[mi] = *(const f16x8*)(sA1 + (wr * 4 + mi) * 512 + lane * 8);
#pragma unroll
      for (int ni = 0; ni < 4; ++ni)
        bf[ni] = *(const f16x8*)(sB1 + (wc * 4 + ni) * 512 + lane * 8);
      if (it2 < 31) {
        const int kt = (2 * it2 + 2) * 32;
        GLDS16(srcA0 + kt, sA0 + dOff);
        GLDS16(srcA1 + kt, sA0 + dOff + 512);
        GLDS16(srcB0 + kt, sB0 + dOff);
        GLDS16(srcB1 + kt, sB0 + dOff + 512);
      }
#pragma unroll
      for (int mi = 0; mi < 4; ++mi)
#pragma unroll
        for (int ni = 0; ni < 4; ++ni)
          acc[mi][ni] = __builtin_amdgcn_mfma_f32_16x16x32_f16(af[mi], bf[ni], acc[mi][ni], 0, 0, 0);
    }
  }
  // epilogue: gelu -> * W2 -> reduce over the 128 n-cols this block owns
  float w2v[4];
#pragma unroll
  for (int ni = 0; ni < 4; ++ni) w2v[ni] = W2[n0 + wc * 64 + ni * 16 + col];
#pragma unroll
  for (int mi = 0; mi < 4; ++mi) {
#pragma unroll
    for (int reg = 0; reg < 4; ++reg) {
      float v = 0.f;
#pragma unroll
      for (int ni = 0; ni < 4; ++ni) v += gelu_f(acc[mi][ni][reg]) * w2v[ni];
      v += __shfl_xor(v, 1);
      v += __shfl_xor(v, 2);
      v += __shfl_xor(v, 4);
      v += __shfl_xor(v, 8);
      if (col == 0)
        atomicAdd(diffz + m0 + wr * 64 + mi * 16 + quad * 4 + reg, v);
    }
  }
}

// ---------------- per-token finalize: one wave per token, 32 tokens/block ----------------
__global__ __launch_bounds__(256) void finalize_kernel(const float* __restrict__ logitsP,
                                                       const float* __restrict__ diffz,
                                                       float* __restrict__ out_idx,
                                                       float* __restrict__ out_scores,
                                                       float* __restrict__ out_probs,
                                                       float* __restrict__ out_imp,
                                                       float* __restrict__ out_load) {
  const int tid  = threadIdx.x;
  const int w    = tid >> 6, lane = tid & 63;
  const size_t PS = (size_t)BS_TOK * NEXP;
  float acc_imp = 0.f, acc_load = 0.f;
  for (int it = 0; it < 8; ++it) {
    const int t    = blockIdx.x * 32 + it * 4 + w;
    const float* lp = logitsP + (size_t)t * NEXP + lane;
    const float L  = ((lp[0] + lp[PS]) + lp[2 * PS]) + lp[3 * PS];
    const float z  = diffz[t];
    const float d  = 1.0f / (1.0f + expf(-z));
    const float l  = L / (1.0f + d);          // TEMP == 1
    // fused top-2 tournament butterfly; key = (value desc, index asc).
    // After 6 steps every lane holds global (v1,i1,v2,i2); v1 doubles as softmax max.
    float v1 = l; int i1 = lane;
    float v2 = -INFINITY; int i2 = 0;
#pragma unroll
    for (int off = 32; off > 0; off >>= 1) {
      const float ov1 = __shfl_xor(v1, off); const int oi1 = __shfl_xor(i1, off);
      const float ov2 = __shfl_xor(v2, off); const int oi2 = __shfl_xor(i2, off);
      const bool bwin = (ov1 > v1) || (ov1 == v1 && oi1 < i1);
      const float w1 = bwin ? ov1 : v1; const int wi1 = bwin ? oi1 : i1;
      const float l1 = bwin ? v1 : ov1; const int li1 = bwin ? i1 : oi1;
      const float c2 = bwin ? ov2 : v2; const int ci2 = bwin ? oi2 : i2;
      const bool s2w = (c2 > l1) || (c2 == l1 && ci2 < li1);
      v2 = s2w ? c2 : l1; i2 = s2w ? ci2 : li1;
      v1 = w1; i1 = wi1;
    }
    // softmax using v1 as max
    float p = expf(l - v1);
    float s = p;
#pragma unroll
    for (int off = 32; off > 0; off >>= 1) s += __shfl_xor(s, off);
    p /= s;
    const float p1 = __shfl(p, i1);
    const float p2 = __shfl(p, i2);
    const float s1 = (1.0f - p1) + p1;        // straight-through, fp32-faithful
    const float s2 = (1.0f - p2) + p2;
    const float den = fmaxf(s1 + s2, 1e-9f);
    if (lane == 0) {
      out_idx[t * 2]        = (float)i1;
      out_idx[t * 2 + 1]    = (float)i2;
      out_scores[t * 2]     = s1 / den;
      out_scores[t * 2 + 1] = s2 / den;
    }
    out_probs[(size_t)t * NEXP + lane] = p;
    acc_imp  += p;
    acc_load += (lane == i1 || lane == i2) ? 1.0f : 0.0f;
  }
  __shared__ float s_imp[256];
  __shared__ float s_hard[256];
  s_imp[tid]  = acc_imp;
  s_hard[tid] = acc_load;
  __syncthreads();
  if (tid < 64) {
    const float inv = 1.0f / (float)BS_TOK;
    const float si = s_imp[tid] + s_imp[64 + tid] + s_imp[128 + tid] + s_imp[192 + tid];
    const float sl = s_hard[tid] + s_hard[64 + tid] + s_hard[128 + tid] + s_hard[192 + tid];
    atomicAdd(out_imp + tid, si * inv);
    atomicAdd(out_load + tid, sl * inv);
  }
}

extern "C" void kernel_launch(void* const* d_in, const int* in_sizes, int n_in,
                              void* d_out, int out_size, void* d_ws, size_t ws_size,
                              hipStream_t stream) {
  (void)in_sizes; (void)n_in; (void)out_size; (void)ws_size;
  const float* X     = (const float*)d_in[0];
  const float* Wg    = (const float*)d_in[1];
  const float* gamma = (const float*)d_in[2];
  const float* beta  = (const float*)d_in[3];
  const float* W1    = (const float*)d_in[4];
  const float* W2    = (const float*)d_in[5];
  float* out = (float*)d_out;

  char* ws = (char*)d_ws;
  _Float16* H       = (_Float16*)(ws);                    // 64 MB
  _Float16* W1h     = (_Float16*)(ws + 67108864ull);      // 4 MB
  float*    logitsP = (float*)  (ws + 71303168ull);       // 16 MB (4 k-split partials)
  float*    diffz   = (float*)  (ws + 88080384ull);       // 64 KB

  // out layout (all float32): idx[32768] | scores[32768] | probs[1048576] | imp[64] | load[64]
  float* out_idx    = out;
  float* out_scores = out + 32768;
  float* out_probs  = out + 65536;
  float* out_imp    = out + 1114112;
  float* out_load   = out + 1114176;

  hipMemsetAsync(diffz, 0, 65536ull, stream);
  hipMemsetAsync(out_imp, 0, 512ull, stream);
  prep_kernel<<<GATE_NB + LN_NB + CAST_NB, 256, 0, stream>>>(X, Wg, gamma, beta, W1,
                                                             H, W1h, logitsP);
  g2_kernel<<<(DHID / 128) * (BS_TOK / 128), 256, 0, stream>>>(H, W1h, W2, diffz);
  finalize_kernel<<<BS_TOK / 32, 256, 0, stream>>>(logitsP, diffz, out_idx, out_scores,
                                                   out_probs, out_imp, out_load);
}